// Round 3
// baseline (178.702 us; speedup 1.0000x reference)
//
#include <hip/hip_runtime.h>

namespace {

constexpr int kN  = 768;
constexpr int kCM = 256;
constexpr int kCZ = 128;
constexpr int kNB = 15;
constexpr int kZRows       = kN * kN;               // 589824
constexpr int kZRowsPerBlk = 16;
constexpr int kZBlocks     = kZRows / kZRowsPerBlk; // 36864
constexpr int kMRowsPerBlk = 8;
constexpr int kMBlocks     = kN / kMRowsPerBlk;     // 96

__device__ __forceinline__ void ld8(const float* p, float* v) {
    const float4 a = reinterpret_cast<const float4*>(p)[0];
    const float4 b = reinterpret_cast<const float4*>(p)[1];
    v[0] = a.x; v[1] = a.y; v[2] = a.z; v[3] = a.w;
    v[4] = b.x; v[5] = b.y; v[6] = b.z; v[7] = b.w;
}

__device__ __forceinline__ void st8(float* p, const float* o) {
    reinterpret_cast<float4*>(p)[0] = make_float4(o[0], o[1], o[2], o[3]);
    reinterpret_cast<float4*>(p)[1] = make_float4(o[4], o[5], o[6], o[7]);
}

} // namespace

__global__ __launch_bounds__(256) void recycling_embedder_kernel(
    const float* __restrict__ m_in, const float* __restrict__ z_in,
    const float* __restrict__ x_in, const float* __restrict__ W_in,
    const float* __restrict__ b_in,
    const float* __restrict__ gm_in, const float* __restrict__ bm_in,
    const float* __restrict__ gz_in, const float* __restrict__ bz_in,
    float* __restrict__ out_m, float* __restrict__ out_z)
{
    const int tid = threadIdx.x;
    const int blk = blockIdx.x;

    if (blk < kZBlocks) {
        // ---------------- z_out = emb(bin(d_ij)) + LayerNorm(z) ----------------
        __shared__ __align__(16) float emb[kNB * kCZ];  // [bin][c]
        __shared__ int p_s[kZRowsPerBlk];

        const int sub = tid & 15;   // lane within row (16 lanes x 8 ch = 128)
        const int rl  = tid >> 4;   // row within block
        const int row = blk * kZRowsPerBlk + rl;

        // main z load issued early (doesn't depend on LDS)
        float v[8];
        ld8(z_in + (size_t)row * kCZ + sub * 8, v);

        // build embedding table: emb[bin*128 + c] = W[c, bin] + b[c]
        for (int idx = tid; idx < kNB * kCZ; idx += 256) {
            const int bin = idx >> 7;
            const int c   = idx & (kCZ - 1);
            emb[idx] = W_in[c * kNB + bin] + b_in[c];
        }

        // 16 threads compute the nearest-bin index for the block's 16 rows
        if (tid < kZRowsPerBlk) {
#pragma clang fp contract(off)
            const int r = blk * kZRowsPerBlk + tid;
            const int i = r / kN;
            const int j = r - i * kN;
            const float d0 = x_in[i * 3 + 0] - x_in[j * 3 + 0];
            const float d1 = x_in[i * 3 + 1] - x_in[j * 3 + 1];
            const float d2 = x_in[i * 3 + 2] - x_in[j * 3 + 2];
            const float s0 = d0 * d0;
            const float s1 = d1 * d1;
            const float s2 = d2 * d2;
            const float d  = sqrtf((s0 + s1) + s2);  // same order as np.sum
            int   best = 0;
            float bv   = fabsf(d - 3.25f);
            for (int k = 1; k < kNB; ++k) {
                const float ad = fabsf(d - (3.25f + 1.25f * (float)k));
                if (ad < bv) { bv = ad; best = k; }  // first-wins like np.argmin
            }
            p_s[tid] = best;
        }

        float s = 0.f, ss = 0.f;
#pragma unroll
        for (int k = 0; k < 8; ++k) { s += v[k]; ss += v[k] * v[k]; }
#pragma unroll
        for (int msk = 1; msk < 16; msk <<= 1) {
            s  += __shfl_xor(s, msk, 64);
            ss += __shfl_xor(ss, msk, 64);
        }
        const float mu  = s * (1.f / kCZ);
        const float var = ss * (1.f / kCZ) - mu * mu;
        const float rs  = rsqrtf(var + 1e-5f);

        float g[8], be[8];
        ld8(gz_in + sub * 8, g);
        ld8(bz_in + sub * 8, be);

        __syncthreads();

        const int p = p_s[rl];
        float e[8];
        ld8(&emb[p * kCZ + sub * 8], e);

        float o[8];
#pragma unroll
        for (int k = 0; k < 8; ++k)
            o[k] = (v[k] - mu) * rs * g[k] + be[k] + e[k];
        st8(out_z + (size_t)row * kCZ + sub * 8, o);
    } else {
        // ---------------- m_out = LayerNorm(m) ----------------
        const int mblk = blk - kZBlocks;
        const int sub  = tid & 31;  // 32 lanes x 8 ch = 256
        const int rl   = tid >> 5;
        const int row  = mblk * kMRowsPerBlk + rl;

        float v[8];
        ld8(m_in + (size_t)row * kCM + sub * 8, v);

        float s = 0.f, ss = 0.f;
#pragma unroll
        for (int k = 0; k < 8; ++k) { s += v[k]; ss += v[k] * v[k]; }
#pragma unroll
        for (int msk = 1; msk < 32; msk <<= 1) {
            s  += __shfl_xor(s, msk, 64);
            ss += __shfl_xor(ss, msk, 64);
        }
        const float mu  = s * (1.f / kCM);
        const float var = ss * (1.f / kCM) - mu * mu;
        const float rs  = rsqrtf(var + 1e-5f);

        float g[8], be[8];
        ld8(gm_in + sub * 8, g);
        ld8(bm_in + sub * 8, be);

        float o[8];
#pragma unroll
        for (int k = 0; k < 8; ++k)
            o[k] = (v[k] - mu) * rs * g[k] + be[k];
        st8(out_m + (size_t)row * kCM + sub * 8, o);
    }
}

extern "C" void kernel_launch(void* const* d_in, const int* in_sizes, int n_in,
                              void* d_out, int out_size, void* d_ws, size_t ws_size,
                              hipStream_t stream) {
    const float* m  = (const float*)d_in[0];
    const float* z  = (const float*)d_in[1];
    const float* x  = (const float*)d_in[2];
    const float* W  = (const float*)d_in[3];
    const float* b  = (const float*)d_in[4];
    const float* gm = (const float*)d_in[5];
    const float* bm = (const float*)d_in[6];
    const float* gz = (const float*)d_in[7];
    const float* bz = (const float*)d_in[8];

    float* out_m = (float*)d_out;
    float* out_z = out_m + kN * kCM;

    recycling_embedder_kernel<<<dim3(kZBlocks + kMBlocks), dim3(256), 0, stream>>>(
        m, z, x, W, b, gm, bm, gz, bz, out_m, out_z);
}

// Round 4
// 143.331 us; speedup vs baseline: 1.2468x; 1.2468x over previous
//
#include <hip/hip_runtime.h>

namespace {

constexpr int kN  = 768;
constexpr int kCM = 256;
constexpr int kCZ = 128;
constexpr int kNB = 15;
constexpr int kZRows       = kN * kN;               // 589824
constexpr int kZRowsPerBlk = 16;
constexpr int kZBlocks     = kZRows / kZRowsPerBlk; // 36864  (= 48 blocks per i-row)
constexpr int kBlksPerI    = kN / kZRowsPerBlk;     // 48
constexpr int kMRowsPerBlk = 8;
constexpr int kMBlocks     = kN / kMRowsPerBlk;     // 96

__device__ __forceinline__ void ld8(const float* p, float* v) {
    const float4 a = reinterpret_cast<const float4*>(p)[0];
    const float4 b = reinterpret_cast<const float4*>(p)[1];
    v[0] = a.x; v[1] = a.y; v[2] = a.z; v[3] = a.w;
    v[4] = b.x; v[5] = b.y; v[6] = b.z; v[7] = b.w;
}

__device__ __forceinline__ void st8(float* p, const float* o) {
    reinterpret_cast<float4*>(p)[0] = make_float4(o[0], o[1], o[2], o[3]);
    reinterpret_cast<float4*>(p)[1] = make_float4(o[4], o[5], o[6], o[7]);
}

} // namespace

// Build emb[bin][c] = W[c, bin] + b[c] once into workspace (15*128 floats).
__global__ __launch_bounds__(256) void build_emb_kernel(
    const float* __restrict__ W_in, const float* __restrict__ b_in,
    float* __restrict__ emb)
{
    const int idx = blockIdx.x * 256 + threadIdx.x;
    if (idx < kNB * kCZ) {
        const int bin = idx >> 7;          // idx / 128
        const int c   = idx & (kCZ - 1);   // idx % 128
        emb[idx] = W_in[c * kNB + bin] + b_in[c];
    }
}

__global__ __launch_bounds__(256) void recycling_embedder_kernel(
    const float* __restrict__ m_in, const float* __restrict__ z_in,
    const float* __restrict__ x_in,
    const float* __restrict__ gm_in, const float* __restrict__ bm_in,
    const float* __restrict__ gz_in, const float* __restrict__ bz_in,
    const float* __restrict__ emb,
    float* __restrict__ out_m, float* __restrict__ out_z)
{
    const int tid = threadIdx.x;
    const int blk = blockIdx.x;

    if (blk < kZBlocks) {
        // -------- z_out = emb[bin(d_ij)] + LayerNorm(z) ; no LDS, no barrier ----
        const int sub = tid & 15;   // lane within row (16 lanes x 8 ch = 128)
        const int rl  = tid >> 4;   // row within block
        const int row = blk * kZRowsPerBlk + rl;

        float v[8];
        ld8(z_in + (size_t)row * kCZ + sub * 8, v);

        // every lane computes its row's nearest-bin index (i uniform per block)
        const int i = blk / kBlksPerI;
        const int j = (blk - i * kBlksPerI) * kZRowsPerBlk + rl;
        int p;
        {
#pragma clang fp contract(off)
            const float d0 = x_in[i * 3 + 0] - x_in[j * 3 + 0];
            const float d1 = x_in[i * 3 + 1] - x_in[j * 3 + 1];
            const float d2 = x_in[i * 3 + 2] - x_in[j * 3 + 2];
            const float s0 = d0 * d0;
            const float s1 = d1 * d1;
            const float s2 = d2 * d2;
            const float d  = sqrtf((s0 + s1) + s2);  // same order as np.sum
            int   best = 0;
            float bv   = fabsf(d - 3.25f);
#pragma unroll
            for (int k = 1; k < kNB; ++k) {
                const float ad = fabsf(d - (3.25f + 1.25f * (float)k));
                if (ad < bv) { bv = ad; best = k; }  // first-wins like np.argmin
            }
            p = best;
        }

        float s = 0.f, ss = 0.f;
#pragma unroll
        for (int k = 0; k < 8; ++k) { s += v[k]; ss += v[k] * v[k]; }
#pragma unroll
        for (int msk = 1; msk < 16; msk <<= 1) {
            s  += __shfl_xor(s, msk, 64);
            ss += __shfl_xor(ss, msk, 64);
        }
        const float mu  = s * (1.f / kCZ);
        const float var = ss * (1.f / kCZ) - mu * mu;
        const float rs  = rsqrtf(var + 1e-5f);

        float g[8], be[8], e[8];
        ld8(gz_in + sub * 8, g);
        ld8(bz_in + sub * 8, be);
        ld8(emb + p * kCZ + sub * 8, e);   // L1-resident 7.5 KB table

        float o[8];
#pragma unroll
        for (int k = 0; k < 8; ++k)
            o[k] = (v[k] - mu) * rs * g[k] + be[k] + e[k];
        st8(out_z + (size_t)row * kCZ + sub * 8, o);
    } else {
        // ---------------- m_out = LayerNorm(m) ----------------
        const int mblk = blk - kZBlocks;
        const int sub  = tid & 31;  // 32 lanes x 8 ch = 256
        const int rl   = tid >> 5;
        const int row  = mblk * kMRowsPerBlk + rl;

        float v[8];
        ld8(m_in + (size_t)row * kCM + sub * 8, v);

        float s = 0.f, ss = 0.f;
#pragma unroll
        for (int k = 0; k < 8; ++k) { s += v[k]; ss += v[k] * v[k]; }
#pragma unroll
        for (int msk = 1; msk < 32; msk <<= 1) {
            s  += __shfl_xor(s, msk, 64);
            ss += __shfl_xor(ss, msk, 64);
        }
        const float mu  = s * (1.f / kCM);
        const float var = ss * (1.f / kCM) - mu * mu;
        const float rs  = rsqrtf(var + 1e-5f);

        float g[8], be[8];
        ld8(gm_in + sub * 8, g);
        ld8(bm_in + sub * 8, be);

        float o[8];
#pragma unroll
        for (int k = 0; k < 8; ++k)
            o[k] = (v[k] - mu) * rs * g[k] + be[k];
        st8(out_m + (size_t)row * kCM + sub * 8, o);
    }
}

extern "C" void kernel_launch(void* const* d_in, const int* in_sizes, int n_in,
                              void* d_out, int out_size, void* d_ws, size_t ws_size,
                              hipStream_t stream) {
    const float* m  = (const float*)d_in[0];
    const float* z  = (const float*)d_in[1];
    const float* x  = (const float*)d_in[2];
    const float* W  = (const float*)d_in[3];
    const float* b  = (const float*)d_in[4];
    const float* gm = (const float*)d_in[5];
    const float* bm = (const float*)d_in[6];
    const float* gz = (const float*)d_in[7];
    const float* bz = (const float*)d_in[8];

    float* emb   = (float*)d_ws;           // 15*128 floats = 7.5 KB
    float* out_m = (float*)d_out;
    float* out_z = out_m + kN * kCM;

    build_emb_kernel<<<dim3((kNB * kCZ + 255) / 256), dim3(256), 0, stream>>>(
        W, b, emb);
    recycling_embedder_kernel<<<dim3(kZBlocks + kMBlocks), dim3(256), 0, stream>>>(
        m, z, x, gm, bm, gz, bz, emb, out_m, out_z);
}

// Round 6
// 109.679 us; speedup vs baseline: 1.6293x; 1.3068x over previous
//
#include <hip/hip_runtime.h>

namespace {

constexpr int kN  = 768;
constexpr int kCM = 256;
constexpr int kCZ = 128;
constexpr int kNB = 15;
constexpr int kZRows       = kN * kN;               // 589824
constexpr int kZRowsPerBlk = 16;
constexpr int kZBlocks     = kZRows / kZRowsPerBlk; // 36864  (= 48 blocks per i-row)
constexpr int kBlksPerI    = kN / kZRowsPerBlk;     // 48
constexpr int kMRowsPerBlk = 8;
constexpr int kMBlocks     = kN / kMRowsPerBlk;     // 96

typedef float f32x4 __attribute__((ext_vector_type(4)));

// lane holds columns [4*sub, 4*sub+4) and [half + 4*sub, half + 4*sub+4):
// each float4 instruction is fully contiguous across the 16-lane row group.
__device__ __forceinline__ void ld8c(const float* rowp, int sub, int half4, float* v) {
    const f32x4* p = reinterpret_cast<const f32x4*>(rowp);
    const f32x4 a = p[sub];
    const f32x4 b = p[sub + half4];
    v[0] = a.x; v[1] = a.y; v[2] = a.z; v[3] = a.w;
    v[4] = b.x; v[5] = b.y; v[6] = b.z; v[7] = b.w;
}

__device__ __forceinline__ void st8c_nt(float* rowp, int sub, int half4, const float* o) {
    f32x4* p = reinterpret_cast<f32x4*>(rowp);
    f32x4 a; a.x = o[0]; a.y = o[1]; a.z = o[2]; a.w = o[3];
    f32x4 b; b.x = o[4]; b.y = o[5]; b.z = o[6]; b.w = o[7];
    __builtin_nontemporal_store(a, p + sub);
    __builtin_nontemporal_store(b, p + sub + half4);
}

} // namespace

// Build emb[bin][c] = W[c, bin] + b[c] once into workspace (15*128 floats).
__global__ __launch_bounds__(256) void build_emb_kernel(
    const float* __restrict__ W_in, const float* __restrict__ b_in,
    float* __restrict__ emb)
{
    const int idx = blockIdx.x * 256 + threadIdx.x;
    if (idx < kNB * kCZ) {
        const int bin = idx >> 7;          // idx / 128
        const int c   = idx & (kCZ - 1);   // idx % 128
        emb[idx] = W_in[c * kNB + bin] + b_in[c];
    }
}

__global__ __launch_bounds__(256) void recycling_embedder_kernel(
    const float* __restrict__ m_in, const float* __restrict__ z_in,
    const float* __restrict__ x_in,
    const float* __restrict__ gm_in, const float* __restrict__ bm_in,
    const float* __restrict__ gz_in, const float* __restrict__ bz_in,
    const float* __restrict__ emb,
    float* __restrict__ out_m, float* __restrict__ out_z)
{
    const int tid = threadIdx.x;
    const int blk = blockIdx.x;

    if (blk < kZBlocks) {
        // -------- z_out = emb[bin(d_ij)] + LayerNorm(z) ; no LDS, no barrier ----
        const int sub = tid & 15;   // lane within row (16 lanes x 2 float4 = 128)
        const int rl  = tid >> 4;   // row within block
        const int row = blk * kZRowsPerBlk + rl;

        float v[8];
        ld8c(z_in + (size_t)row * kCZ, sub, 16, v);

        // every lane computes its row's nearest-bin index (i uniform per block)
        const int i = blk / kBlksPerI;
        const int j = (blk - i * kBlksPerI) * kZRowsPerBlk + rl;
        int p;
        {
#pragma clang fp contract(off)
            const float d0 = x_in[i * 3 + 0] - x_in[j * 3 + 0];
            const float d1 = x_in[i * 3 + 1] - x_in[j * 3 + 1];
            const float d2 = x_in[i * 3 + 2] - x_in[j * 3 + 2];
            const float s0 = d0 * d0;
            const float s1 = d1 * d1;
            const float s2 = d2 * d2;
            const float d  = sqrtf((s0 + s1) + s2);  // same order as np.sum
            int   best = 0;
            float bv   = fabsf(d - 3.25f);
#pragma unroll
            for (int k = 1; k < kNB; ++k) {
                const float ad = fabsf(d - (3.25f + 1.25f * (float)k));
                if (ad < bv) { bv = ad; best = k; }  // first-wins like np.argmin
            }
            p = best;
        }

        float s = 0.f, ss = 0.f;
#pragma unroll
        for (int k = 0; k < 8; ++k) { s += v[k]; ss += v[k] * v[k]; }
#pragma unroll
        for (int msk = 1; msk < 16; msk <<= 1) {
            s  += __shfl_xor(s, msk, 64);
            ss += __shfl_xor(ss, msk, 64);
        }
        const float mu  = s * (1.f / kCZ);
        const float var = ss * (1.f / kCZ) - mu * mu;
        const float rs  = rsqrtf(var + 1e-5f);

        float g[8], be[8], e[8];
        ld8c(gz_in, sub, 16, g);
        ld8c(bz_in, sub, 16, be);
        ld8c(emb + p * kCZ, sub, 16, e);   // L1-resident 7.5 KB table

        float o[8];
#pragma unroll
        for (int k = 0; k < 8; ++k)
            o[k] = (v[k] - mu) * rs * g[k] + be[k] + e[k];
        st8c_nt(out_z + (size_t)row * kCZ, sub, 16, o);
    } else {
        // ---------------- m_out = LayerNorm(m) ----------------
        const int mblk = blk - kZBlocks;
        const int sub  = tid & 31;  // 32 lanes x 2 float4 = 256
        const int rl   = tid >> 5;
        const int row  = mblk * kMRowsPerBlk + rl;

        float v[8];
        ld8c(m_in + (size_t)row * kCM, sub, 32, v);

        float s = 0.f, ss = 0.f;
#pragma unroll
        for (int k = 0; k < 8; ++k) { s += v[k]; ss += v[k] * v[k]; }
#pragma unroll
        for (int msk = 1; msk < 32; msk <<= 1) {
            s  += __shfl_xor(s, msk, 64);
            ss += __shfl_xor(ss, msk, 64);
        }
        const float mu  = s * (1.f / kCM);
        const float var = ss * (1.f / kCM) - mu * mu;
        const float rs  = rsqrtf(var + 1e-5f);

        float g[8], be[8];
        ld8c(gm_in, sub, 32, g);
        ld8c(bm_in, sub, 32, be);

        float o[8];
#pragma unroll
        for (int k = 0; k < 8; ++k)
            o[k] = (v[k] - mu) * rs * g[k] + be[k];
        st8c_nt(out_m + (size_t)row * kCM, sub, 32, o);
    }
}

extern "C" void kernel_launch(void* const* d_in, const int* in_sizes, int n_in,
                              void* d_out, int out_size, void* d_ws, size_t ws_size,
                              hipStream_t stream) {
    const float* m  = (const float*)d_in[0];
    const float* z  = (const float*)d_in[1];
    const float* x  = (const float*)d_in[2];
    const float* W  = (const float*)d_in[3];
    const float* b  = (const float*)d_in[4];
    const float* gm = (const float*)d_in[5];
    const float* bm = (const float*)d_in[6];
    const float* gz = (const float*)d_in[7];
    const float* bz = (const float*)d_in[8];

    float* emb   = (float*)d_ws;           // 15*128 floats = 7.5 KB
    float* out_m = (float*)d_out;
    float* out_z = out_m + kN * kCM;

    build_emb_kernel<<<dim3((kNB * kCZ + 255) / 256), dim3(256), 0, stream>>>(
        W, b, emb);
    recycling_embedder_kernel<<<dim3(kZBlocks + kMBlocks), dim3(256), 0, stream>>>(
        m, z, x, gm, bm, gz, bz, emb, out_m, out_z);
}